// Round 5
// baseline (43.183 us; speedup 1.0000x reference)
//
#include <hip/hip_runtime.h>
#include <hip/hip_bf16.h>

// LengthRegulator: x [B=32, S=1024, D=384] f32, durations [B,S] int (0..7).
// Output 0: out [B, L, D] f32, L = max_b sum_t dur[b,t] (derived from out_size).
// Output 1: out_lens [B] (float, tail of d_out).
//
// Round 5: software-pipeline the chunk copy — resolve all 12 source addrs,
// issue all 12 loads into registers (192 B of outstanding reads per thread),
// then all 12 non-temporal stores. Removes per-iteration load->store serial
// dependency; everything else as round 4.

#define LR_B 32
#define LR_S 1024
#define LR_D 384           // floats per row = 96 float4
#define LR_V4 (LR_D / 4)   // 96
#define ROWS_PB 32         // output rows per block
#define ITERS (ROWS_PB * LR_V4 / 256)  // 12

typedef float f32x4 __attribute__((ext_vector_type(4)));

__global__ __launch_bounds__(256) void lr_fused_kernel(
    const f32x4* __restrict__ x4, const int* __restrict__ dur,
    f32x4* __restrict__ out4, float* __restrict__ out_tail, int L) {
  __shared__ int wsum[4];        // 4 wave totals (256 threads)
  __shared__ int lidx[ROWS_PB];  // source step per output row in this chunk
  const int b = blockIdx.y;
  const int r0 = blockIdx.x * ROWS_PB;
  const int t = threadIdx.x;
  const int wave = t >> 6, lane = t & 63;

  // ---- per-batch cumsum (redundant per block; 4 KB, L2-hit) ----
  const int4 d4 = ((const int4*)(dur + b * LR_S))[t];  // elems [4t, 4t+4)
  const int e0 = d4.x, e1 = e0 + d4.y, e2 = e1 + d4.z, e3 = e2 + d4.w;
  int v = e3;
#pragma unroll
  for (int off = 1; off < 64; off <<= 1) {
    int n = __shfl_up(v, off, 64);
    if (lane >= off) v += n;
  }
  if (lane == 63) wsum[wave] = v;
  if (t < ROWS_PB) lidx[t] = -1;
  __syncthreads();

  int woff = 0, tot = 0;
#pragma unroll
  for (int w = 0; w < 4; ++w) {
    int s = wsum[w];
    if (w < wave) woff += s;
    tot += s;
  }
  const int base = woff + v - e3;  // exclusive prefix of this thread's 4 elems

  // ---- scatter inverse map for rows [r0, r0+ROWS_PB) ----
  const int r1 = min(r0 + ROWS_PB, L);
  const int starts[4] = {base, base + e0, base + e1, base + e2};
  const int ends[4]   = {base + e0, base + e1, base + e2, base + e3};
#pragma unroll
  for (int k = 0; k < 4; ++k) {
    const int s = max(starts[k], r0), e = min(ends[k], r1);
    for (int j = s; j < e; ++j) lidx[j - r0] = t * 4 + k;
  }
  __syncthreads();

  // ---- chunk copy: resolve -> load all -> store all ----
  const size_t obase = ((size_t)b * L + r0) * LR_V4;
  const size_t xbase = (size_t)b * LR_S * LR_V4;
  const bool full = (r1 - r0) == ROWS_PB;  // uniform across block

  int st[ITERS];
  int vv[ITERS];
#pragma unroll
  for (int i = 0; i < ITERS; ++i) {
    const int p = i * 256 + t;
    const int r = p / LR_V4;          // const divisor -> magic mul
    vv[i] = p - r * LR_V4;
    st[i] = (full || r0 + r < L) ? lidx[r] : -2;  // -2: out of range, skip store
  }

  f32x4 val[ITERS];
#pragma unroll
  for (int i = 0; i < ITERS; ++i) {
    val[i] = (st[i] < 0) ? (f32x4){0.f, 0.f, 0.f, 0.f}
                         : x4[xbase + (size_t)st[i] * LR_V4 + vv[i]];
  }

#pragma unroll
  for (int i = 0; i < ITERS; ++i) {
    if (st[i] != -2)
      __builtin_nontemporal_store(val[i], &out4[obase + i * 256 + t]);
  }

  if (blockIdx.x == 0 && t == 0) out_tail[b] = (float)tot;
}

extern "C" void kernel_launch(void* const* d_in, const int* in_sizes, int n_in,
                              void* d_out, int out_size, void* d_ws, size_t ws_size,
                              hipStream_t stream) {
  const float* x = (const float*)d_in[0];
  const int* dur = (const int*)d_in[1];
  float* out = (float*)d_out;

  // out_size = B*L*D + B  ->  L
  const int L = (out_size - LR_B) / (LR_B * LR_D);
  float* out_tail = out + (size_t)LR_B * L * LR_D;

  const int nchunks = (L + ROWS_PB - 1) / ROWS_PB;
  dim3 grid(nchunks, LR_B);
  lr_fused_kernel<<<grid, 256, 0, stream>>>(
      (const f32x4*)x, dur, (f32x4*)out, out_tail, L);
}

// Round 6
// 40.727 us; speedup vs baseline: 1.0603x; 1.0603x over previous
//
#include <hip/hip_runtime.h>
#include <hip/hip_bf16.h>

// LengthRegulator: x [B=32, S=1024, D=384] f32, durations [B,S] int (0..7).
// Output 0: out [B, L, D] f32, L = max_b sum_t dur[b,t] (derived from out_size).
// Output 1: out_lens [B] (float, tail of d_out).
//
// Round 6: REVERT to round-4 fused kernel (40.8 us) — round 5's load/store
// batching regressed (43.2 us): the compiler's per-iteration interleave was
// already optimally pipelined, and register-batching bunched store traffic.
// Single fused kernel: each block redundantly scans its batch's durations
// (4 KB, L2-resident; int4 loads + wave shfl scan), builds the inverse map
// for its own 32-row output chunk in LDS by scatter, then stream-copies.

#define LR_B 32
#define LR_S 1024
#define LR_D 384           // floats per row = 96 float4
#define LR_V4 (LR_D / 4)   // 96
#define ROWS_PB 32         // output rows per block

typedef float f32x4 __attribute__((ext_vector_type(4)));

__global__ __launch_bounds__(256) void lr_fused_kernel(
    const f32x4* __restrict__ x4, const int* __restrict__ dur,
    f32x4* __restrict__ out4, float* __restrict__ out_tail, int L) {
  __shared__ int wsum[4];        // 4 wave totals (256 threads)
  __shared__ int lidx[ROWS_PB];  // source step per output row in this chunk
  const int b = blockIdx.y;
  const int r0 = blockIdx.x * ROWS_PB;
  const int t = threadIdx.x;
  const int wave = t >> 6, lane = t & 63;

  // ---- per-batch cumsum (redundant per block; 4 KB, L2-hit) ----
  const int4 d4 = ((const int4*)(dur + b * LR_S))[t];  // elems [4t, 4t+4)
  const int e0 = d4.x, e1 = e0 + d4.y, e2 = e1 + d4.z, e3 = e2 + d4.w;
  int v = e3;
#pragma unroll
  for (int off = 1; off < 64; off <<= 1) {
    int n = __shfl_up(v, off, 64);
    if (lane >= off) v += n;
  }
  if (lane == 63) wsum[wave] = v;
  if (t < ROWS_PB) lidx[t] = -1;
  __syncthreads();

  int woff = 0, tot = 0;
#pragma unroll
  for (int w = 0; w < 4; ++w) {
    int s = wsum[w];
    if (w < wave) woff += s;
    tot += s;
  }
  const int base = woff + v - e3;  // exclusive prefix of this thread's 4 elems

  // ---- scatter inverse map for rows [r0, r0+ROWS_PB) ----
  const int r1 = min(r0 + ROWS_PB, L);
  const int starts[4] = {base, base + e0, base + e1, base + e2};
  const int ends[4]   = {base + e0, base + e1, base + e2, base + e3};
#pragma unroll
  for (int k = 0; k < 4; ++k) {
    const int s = max(starts[k], r0), e = min(ends[k], r1);
    for (int j = s; j < e; ++j) lidx[j - r0] = t * 4 + k;
  }
  __syncthreads();

  // ---- stream-copy the chunk: ROWS_PB rows x 96 float4 ----
  const size_t obase = ((size_t)b * L + r0) * LR_V4;
  const size_t xbase = (size_t)b * LR_S * LR_V4;
#pragma unroll
  for (int i = 0; i < ROWS_PB * LR_V4 / 256; ++i) {
    const int p = i * 256 + t;        // 0 .. ROWS_PB*96-1
    const int r = p / LR_V4;          // const divisor -> magic mul
    const int vv = p - r * LR_V4;
    if (r0 + r >= L) continue;        // tail-chunk guard
    const int st = lidx[r];
    f32x4 val = (st < 0) ? (f32x4){0.f, 0.f, 0.f, 0.f}
                         : x4[xbase + (size_t)st * LR_V4 + vv];
    __builtin_nontemporal_store(val, &out4[obase + p]);
  }

  if (blockIdx.x == 0 && t == 0) out_tail[b] = (float)tot;
}

extern "C" void kernel_launch(void* const* d_in, const int* in_sizes, int n_in,
                              void* d_out, int out_size, void* d_ws, size_t ws_size,
                              hipStream_t stream) {
  const float* x = (const float*)d_in[0];
  const int* dur = (const int*)d_in[1];
  float* out = (float*)d_out;

  // out_size = B*L*D + B  ->  L
  const int L = (out_size - LR_B) / (LR_B * LR_D);
  float* out_tail = out + (size_t)LR_B * L * LR_D;

  const int nchunks = (L + ROWS_PB - 1) / ROWS_PB;
  dim3 grid(nchunks, LR_B);
  lr_fused_kernel<<<grid, 256, 0, stream>>>(
      (const f32x4*)x, dur, (f32x4*)out, out_tail, L);
}